// Round 4
// baseline (445.887 us; speedup 1.0000x reference)
//
#include <hip/hip_runtime.h>

// FFT-conv: y = real(ifft2( sum_i K[o,i] * fft2(x[b,i]) )) + bias
// B=32, CIN=64, COUT=128, H=W=56.
// Hermitian symmetry: only spectral rows kh=0..28 stored (1624 bins).
// Pipeline: ksetup -> kfwd (FFT2, bf16 MFMA, packed bf16 out)
//           -> kpack/kmix (x2 o-halves; K repack + MFMA channel mix)
//           -> kinv (inverse FFT2, bf16 MFMA).

#define HH 56
#define NF 3136      // 56*56
#define KH 29        // stored spectral rows
#define NFH 1624     // 29*56
constexpr int B = 32, CIN = 64, COUT = 128;
constexpr float PI2 = 6.283185307179586f;

typedef __attribute__((ext_vector_type(8))) short s8v;   // 8 x bf16 (A/B frag)
typedef __attribute__((ext_vector_type(4))) float f4v;   // C/D frag

#define MFMA(a, b, c) __builtin_amdgcn_mfma_f32_16x16x32_bf16(a, b, c, 0, 0, 0)

__device__ __host__ inline short f2bf(float f) {
    unsigned u = __builtin_bit_cast(unsigned, f);
    u += 0x7fffu + ((u >> 16) & 1u);      // round-to-nearest-even
    return (short)(u >> 16);
}

__device__ inline s8v bfneg(s8v v) {      // bf16 negate = flip sign bits
    int4 u = __builtin_bit_cast(int4, v);
    u.x ^= 0x80008000; u.y ^= 0x80008000; u.z ^= 0x80008000; u.w ^= 0x80008000;
    return __builtin_bit_cast(s8v, u);
}

// ---------------------------------------------------------------------------
// Constant pool in d_ws (shorts):
//   Cw  [64][72] @0     : cos(2*pi*m*n/56), m<56&&n<56 else 0   (symmetric)
//   Sw  [64][72] @4608  : +sin(...)
//   SwN [64][72] @9216  : -sin(...)
//   A2C [64][40] @13824 : wgt(kh)*cos(2*pi*h*kh/56)/3136  (h<56,kh<29 else 0)
//   A2S [64][40] @16384 : -wgt(kh)*sin(...)/3136
__global__ __launch_bounds__(256) void ksetup(short* __restrict__ cpool) {
    int i = blockIdx.x * 256 + threadIdx.x;
    if (i < 4608) {
        int m = i / 72, n = i % 72;
        float c = 0.f, s = 0.f;
        if (m < 56 && n < 56) {
            float ang = PI2 * (float)((m * n) % 56) / 56.f;
            c = cosf(ang); s = sinf(ang);
        }
        cpool[i]        = f2bf(c);
        cpool[4608 + i] = f2bf(s);
        cpool[9216 + i] = f2bf(-s);
    } else if (i < 7168) {
        int j = i - 4608;
        int h = j / 40, kh = j % 40;
        float c = 0.f, s = 0.f;
        if (h < 56 && kh < 29) {
            float w = (kh == 0 || kh == 28) ? 1.f : 2.f;
            float ang = PI2 * (float)((h * kh) % 56) / 56.f;
            float sc = w * (1.f / 3136.f);
            c = sc * cosf(ang);
            s = -sc * sinf(ang);
        }
        cpool[13824 + j] = f2bf(c);
        cpool[16384 + j] = f2bf(s);
    }
}

// ---------------------------------------------------------------------------
// Kernel A: forward FFT2 per (b,i) image via two MFMA GEMM passes.
// Output: packed bf16 Xp[plane][f][img], img = b*64+i = blockIdx.x.
__global__ __launch_bounds__(256) void kfwd(const float* __restrict__ x,
                                            const short* __restrict__ cpool,
                                            short* __restrict__ Xp) {
    __shared__ __align__(16) short Cw[4608], Sw[4608], SwN[4608];
    __shared__ __align__(16) short xs[4608];             // [h][72] bf16
    __shared__ __align__(16) short T1r[4608], T1i[4608]; // S1 transposed [kw][72]
    const int tid = threadIdx.x;
    {
        const int4* src = (const int4*)cpool;
        for (int i = tid; i < 576; i += 256) {
            ((int4*)Cw)[i]  = src[i];
            ((int4*)Sw)[i]  = src[576 + i];
            ((int4*)SwN)[i] = src[1152 + i];
        }
    }
    for (int i = tid; i < 2304; i += 256) ((int*)xs)[i] = 0;
    __syncthreads();
    const float* xp = x + (size_t)blockIdx.x * NF;
    for (int i = tid; i < NF; i += 256) {
        int h = i / 56, w = i % 56;
        xs[h * 72 + w] = f2bf(xp[i]);
    }
    __syncthreads();

    const int lane = tid & 63;
    const int nt = tid >> 6;
    const int q = lane >> 4, l15 = lane & 15;

    // ---- stage 1: A = xs[h][w], B = (C - iS)[w][kw]
    f4v aR[4] = {}, aI[4] = {};
    for (int ks = 0; ks < 2; ++ks) {
        const int bo = (nt * 16 + l15) * 72 + ks * 32 + q * 8;
        s8v bC = *(const s8v*)&Cw[bo];
        s8v bS = *(const s8v*)&SwN[bo];
        for (int mt = 0; mt < 4; ++mt) {
            s8v a = *(const s8v*)&xs[(mt * 16 + l15) * 72 + ks * 32 + q * 8];
            aR[mt] = MFMA(a, bC, aR[mt]);
            aI[mt] = MFMA(a, bS, aI[mt]);
        }
    }
    for (int mt = 0; mt < 4; ++mt)
        for (int r = 0; r < 4; ++r) {
            int o = (nt * 16 + l15) * 72 + mt * 16 + q * 4 + r;  // [kw][h]
            T1r[o] = f2bf(aR[mt][r]);
            T1i[o] = f2bf(aI[mt][r]);
        }
    __syncthreads();

    // ---- stage 2: Xr = C2*S1r + S2*S1i ;  Xi = C2*S1i - S2*S1r
    f4v xr[2] = {}, xi2[2] = {};
    for (int ks = 0; ks < 2; ++ks) {
        const int bo = (nt * 16 + l15) * 72 + ks * 32 + q * 8;
        s8v br = *(const s8v*)&T1r[bo];
        s8v bi = *(const s8v*)&T1i[bo];
        for (int mt = 0; mt < 2; ++mt) {
            const int ao = (mt * 16 + l15) * 72 + ks * 32 + q * 8;
            s8v aC  = *(const s8v*)&Cw[ao];
            s8v aS  = *(const s8v*)&Sw[ao];
            s8v aSN = *(const s8v*)&SwN[ao];
            xr[mt]  = MFMA(aC, br, xr[mt]);
            xr[mt]  = MFMA(aS, bi, xr[mt]);
            xi2[mt] = MFMA(aC, bi, xi2[mt]);
            xi2[mt] = MFMA(aSN, br, xi2[mt]);
        }
    }
    const int kw = nt * 16 + l15;
    const int img = blockIdx.x;
    if (kw < 56) {
        for (int mt = 0; mt < 2; ++mt)
            for (int r = 0; r < 4; ++r) {
                int kh = mt * 16 + q * 4 + r;
                if (kh < 29) {
                    int f = kh * 56 + kw;
                    Xp[(size_t)f * 2048 + img]                    = f2bf(xr[mt][r]);
                    Xp[(size_t)NFH * 2048 + (size_t)f * 2048 + img] = f2bf(xi2[mt][r]);
                }
            }
    }
}

// ---------------------------------------------------------------------------
// Kernel P: repack one o-half of K (used spectral half) to bf16
// Kp[plane][f][o_local 0..63][i 0..63].  grid (64 o, 7 f-chunks, 2 planes).
__global__ __launch_bounds__(256) void kpack(const float* __restrict__ Kr,
                                             const float* __restrict__ Ki,
                                             short* __restrict__ Kp,
                                             int o_base) {
    __shared__ __align__(16) short Ls[232][72];   // [f_local][i] bf16
    const int o_local = blockIdx.x, fc = blockIdx.y, plane = blockIdx.z;
    const int o = o_base + o_local;
    const float* src = plane ? Ki : Kr;
    const int tid = threadIdx.x;

    // read: 64 rows (i) x 58 float4 (232 f), fully coalesced per row
    for (int idx = tid; idx < 3712; idx += 256) {
        const int i = idx / 58, c = idx % 58;
        const float4 v = *(const float4*)&src[(size_t)(o * 64 + i) * NF + fc * 232 + c * 4];
        Ls[c * 4 + 0][i] = f2bf(v.x);
        Ls[c * 4 + 1][i] = f2bf(v.y);
        Ls[c * 4 + 2][i] = f2bf(v.z);
        Ls[c * 4 + 3][i] = f2bf(v.w);
    }
    __syncthreads();
    // write: 232 f x 8 int4 -> full 128-B lines of Kp
    for (int idx = tid; idx < 1856; idx += 256) {
        const int f = idx >> 3, io = idx & 7;
        int4 v = *(const int4*)&Ls[f][io * 8];
        *(int4*)&Kp[((size_t)(plane * NFH + fc * 232 + f) * 64 + o_local) * 64 + io * 8] = v;
    }
}

// ---------------------------------------------------------------------------
// Kernel B: channel mix, bf16 MFMA.  Per block: 4 bins x 16 o x 32 b, K=i=64.
// Y[b,o] = sum_i X[b,i]*K[i,o] complex; A=X (M=b), B=K (N=o).
// grid (406 f-blocks, 4 o-groups); call twice with o_base = 0, 64.
__global__ __launch_bounds__(256) void kmix(const short* __restrict__ Xp,
                                            const short* __restrict__ Kp,
                                            short* __restrict__ Yp,
                                            int o_base) {
    __shared__ __align__(16) short Xs[2][4][32][72];  // [plane][bin][b][i]
    __shared__ __align__(16) short Ks[2][4][16][72];  // [plane][bin][o][i]
    const int f0 = blockIdx.x * 4;
    const int oy = blockIdx.y;
    const int tid = threadIdx.x;

    // stage X: 256 rows x 8 int4
    for (int idx = tid; idx < 2048; idx += 256) {
        const int r = idx >> 3, c = idx & 7;
        const int plane = r >> 7, ff = (r >> 5) & 3, b = r & 31;
        const size_t g = ((size_t)(plane * NFH + f0 + ff) * 2048) + b * 64 + c * 8;
        *(int4*)&Xs[plane][ff][b][c * 8] = *(const int4*)&Xp[g];
    }
    // stage K: 128 rows x 8 int4
    for (int idx = tid; idx < 1024; idx += 256) {
        const int r = idx >> 3, c = idx & 7;
        const int plane = r >> 6, ff = (r >> 4) & 3, ol = r & 15;
        const size_t g = ((size_t)(plane * NFH + f0 + ff) * 64 + oy * 16 + ol) * 64 + c * 8;
        *(int4*)&Ks[plane][ff][ol][c * 8] = *(const int4*)&Kp[g];
    }
    __syncthreads();

    const int lane = tid & 63;
    const int w = tid >> 6;             // wave -> bin
    const int q = lane >> 4, l15 = lane & 15;

    f4v Cr[2] = {}, Ci[2] = {};
    for (int ks = 0; ks < 2; ++ks) {
        s8v Br = *(const s8v*)&Ks[0][w][l15][ks * 32 + q * 8];
        s8v Bi = *(const s8v*)&Ks[1][w][l15][ks * 32 + q * 8];
        for (int mt = 0; mt < 2; ++mt) {
            s8v Ar = *(const s8v*)&Xs[0][w][mt * 16 + l15][ks * 32 + q * 8];
            s8v Ai = *(const s8v*)&Xs[1][w][mt * 16 + l15][ks * 32 + q * 8];
            Cr[mt] = MFMA(Ar, Br, Cr[mt]);
            Cr[mt] = MFMA(bfneg(Ai), Bi, Cr[mt]);
            Ci[mt] = MFMA(Ar, Bi, Ci[mt]);
            Ci[mt] = MFMA(Ai, Br, Ci[mt]);
        }
    }
    const int f = f0 + w;
    const int o = o_base + oy * 16 + l15;
    for (int mt = 0; mt < 2; ++mt)
        for (int r = 0; r < 4; ++r) {
            const int b = mt * 16 + q * 4 + r;
            const size_t img = (size_t)b * COUT + o;
            Yp[img * NFH + f]                        = f2bf(Cr[mt][r]);
            Yp[(size_t)4096 * NFH + img * NFH + f]   = f2bf(Ci[mt][r]);
        }
}

// ---------------------------------------------------------------------------
// Kernel C: inverse FFT2 per (b,o) image via two MFMA GEMM passes + fold.
__global__ __launch_bounds__(256) void kinv(const short* __restrict__ Yp,
                                            const short* __restrict__ cpool,
                                            const float* __restrict__ bias,
                                            float* __restrict__ out) {
    __shared__ __align__(16) short Cw[4608], Sw[4608], SwN[4608];
    __shared__ __align__(16) short A2C[2560], A2S[2560];
    __shared__ __align__(16) short Yr[2304], Yi[2304];   // [kh][72]
    __shared__ __align__(16) short ZTr[2560], ZTi[2560]; // [w][40]
    const int tid = threadIdx.x;
    {
        const int4* src = (const int4*)cpool;
        for (int i = tid; i < 576; i += 256) {
            ((int4*)Cw)[i]  = src[i];
            ((int4*)Sw)[i]  = src[576 + i];
            ((int4*)SwN)[i] = src[1152 + i];
        }
        for (int i = tid; i < 320; i += 256) {
            ((int4*)A2C)[i] = src[1728 + i];
            ((int4*)A2S)[i] = src[2048 + i];
        }
    }
    for (int i = tid; i < 1152; i += 256) { ((int*)Yr)[i] = 0; ((int*)Yi)[i] = 0; }
    __syncthreads();
    const short* ypr = Yp + (size_t)blockIdx.x * NFH;
    const short* ypi = Yp + (size_t)4096 * NFH + (size_t)blockIdx.x * NFH;
    for (int f = tid; f < NFH; f += 256) {
        int kh = f / 56, kw = f % 56;
        Yr[kh * 72 + kw] = ypr[f];
        Yi[kh * 72 + kw] = ypi[f];
    }
    __syncthreads();

    const int lane = tid & 63;
    const int nt = tid >> 6;
    const int q = lane >> 4, l15 = lane & 15;

    // ---- inv1: Zr = Yr*C - Yi*S ;  Zi = Yr*S + Yi*C
    f4v zr[2] = {}, zi[2] = {};
    for (int ks = 0; ks < 2; ++ks) {
        const int bo = (nt * 16 + l15) * 72 + ks * 32 + q * 8;
        s8v bC  = *(const s8v*)&Cw[bo];
        s8v bS  = *(const s8v*)&Sw[bo];
        s8v bSN = *(const s8v*)&SwN[bo];
        for (int mt = 0; mt < 2; ++mt) {
            const int ao = (mt * 16 + l15) * 72 + ks * 32 + q * 8;
            s8v ar = *(const s8v*)&Yr[ao];
            s8v ai = *(const s8v*)&Yi[ao];
            zr[mt] = MFMA(ar, bC, zr[mt]);
            zr[mt] = MFMA(ai, bSN, zr[mt]);
            zi[mt] = MFMA(ar, bS, zi[mt]);
            zi[mt] = MFMA(ai, bC, zi[mt]);
        }
    }
    for (int mt = 0; mt < 2; ++mt)
        for (int r = 0; r < 4; ++r) {
            int o = (nt * 16 + l15) * 40 + mt * 16 + q * 4 + r;  // [w][kh]
            ZTr[o] = f2bf(zr[mt][r]);
            ZTi[o] = f2bf(zi[mt][r]);
        }
    __syncthreads();

    // ---- inv2: A = A2C/A2S [h][kh], B = Z[kh][w]
    f4v yv[4] = {};
    {
        const int bo = (nt * 16 + l15) * 40 + q * 8;
        s8v br = *(const s8v*)&ZTr[bo];
        s8v bi = *(const s8v*)&ZTi[bo];
        for (int mt = 0; mt < 4; ++mt) {
            const int ao = (mt * 16 + l15) * 40 + q * 8;
            s8v ac  = *(const s8v*)&A2C[ao];
            s8v as_ = *(const s8v*)&A2S[ao];
            yv[mt] = MFMA(ac, br, yv[mt]);
            yv[mt] = MFMA(as_, bi, yv[mt]);
        }
    }
    const float bv = bias[blockIdx.x & (COUT - 1)];
    float* opx = out + (size_t)blockIdx.x * NF;
    const int w = nt * 16 + l15;
    if (w < 56) {
        for (int mt = 0; mt < 4; ++mt)
            for (int r = 0; r < 4; ++r) {
                int h = mt * 16 + q * 4 + r;
                if (h < 56) opx[h * 56 + w] = yv[mt][r] + bv;
            }
    }
}

// ---------------------------------------------------------------------------
extern "C" void kernel_launch(void* const* d_in, const int* in_sizes, int n_in,
                              void* d_out, int out_size, void* d_ws, size_t ws_size,
                              hipStream_t stream) {
    const float* x    = (const float*)d_in[0];
    const float* Kr   = (const float*)d_in[1];
    const float* Ki   = (const float*)d_in[2];
    const float* bias = (const float*)d_in[3];

    // d_ws layout (bytes):
    //   cpool  @0         : 40960
    //   Xp     @40960     : 2 * 1624 * 2048 * 2  = 13,307,904
    //   Kp     @13348864  : 2 * 1624 * 64 * 64*2 = 26,607,616  (one o-half)
    //   Yp     @39956480  : 2 * 4096 * 1624 * 2  = 26,607,616
    short* cpool = (short*)d_ws;
    short* Xp    = (short*)((char*)d_ws + 40960);
    short* Kp    = (short*)((char*)d_ws + 13348864);
    short* Yp    = (short*)((char*)d_ws + 39956480);

    hipLaunchKernelGGL(ksetup, dim3(28), dim3(256), 0, stream, cpool);
    hipLaunchKernelGGL(kfwd, dim3(B * CIN), dim3(256), 0, stream, x, cpool, Xp);
    hipLaunchKernelGGL(kpack, dim3(64, 7, 2), dim3(256), 0, stream, Kr, Ki, Kp, 0);
    hipLaunchKernelGGL(kmix, dim3(406, 4), dim3(256), 0, stream, Xp, Kp, Yp, 0);
    hipLaunchKernelGGL(kpack, dim3(64, 7, 2), dim3(256), 0, stream, Kr, Ki, Kp, 64);
    hipLaunchKernelGGL(kmix, dim3(406, 4), dim3(256), 0, stream, Xp, Kp, Yp, 64);
    hipLaunchKernelGGL(kinv, dim3(B * COUT), dim3(256), 0, stream,
                       Yp, cpool, bias, (float*)d_out);
}